// Round 1
// baseline (405.826 us; speedup 1.0000x reference)
//
#include <hip/hip_runtime.h>
#include <cstdint>

// ---------------- problem constants ----------------
constexpr int RS  = 48;    // sigma ranks
constexpr int RC  = 144;   // feature ranks
constexpr int PP  = 27;    // feats dim
constexpr int NV  = 128;   // voxels per axis
constexpr int CHN = 128;   // MLP hidden

// ---------------- ws layout (bf16 element offsets) ----------------
// sigmaT [3][128 vox][64 ranks (48 + zero pad)]
constexpr int SIG_E  = 0;                      // 3*128*64  = 24576
// featT  [3][128 vox][160 ranks (144 + zero pad)]
constexpr int FEAT_E = 24576;                  // 3*128*160 = 61440
// B frags  [kt=5][nt=2][lane=64][e=8]
constexpr int BF_E   = 86016;                  // 5120
// W1 frags [kt=4][nt=8][64][8]  (rows permuted to interleaved-encode order)
constexpr int W1_E   = 91136;                  // 16384
// W2 frags [4][8][64][8]
constexpr int W2_E   = 107520;                 // 16384
// W3 frags [kt=4][64][8] (cols 3..15 zero)
constexpr int W3_E   = 123904;                 // 2048
constexpr int TOT_E  = 125952;                 // ~246 KB of ws

typedef __attribute__((ext_vector_type(8))) short short8;
typedef __attribute__((ext_vector_type(4))) float f32x4;
typedef __attribute__((ext_vector_type(2))) unsigned int u32x2;
typedef __attribute__((ext_vector_type(4))) unsigned int u32x4;

__device__ __forceinline__ short f2bf(float f) {
    unsigned int u = __builtin_bit_cast(unsigned int, f);
    u += 0x7fffu + ((u >> 16) & 1u);           // RNE
    return (short)(u >> 16);
}
__device__ __forceinline__ float bf2f(short s) {
    unsigned int u = ((unsigned int)(unsigned short)s) << 16;
    return __builtin_bit_cast(float, u);
}

// ---------------- prep: build bf16 tables + fragment-layout weights ----------------
__global__ void prep_kernel(const float* __restrict__ sigma, const float* __restrict__ feature,
                            const float* __restrict__ Bm, const float* __restrict__ W1,
                            const float* __restrict__ W2, const float* __restrict__ W3,
                            short* __restrict__ ws) {
    int idx = blockIdx.x * 256 + threadIdx.x;
    if (idx >= TOT_E) return;
    float val = 0.f;
    if (idx < FEAT_E) {                         // sigmaT
        int a = idx / 8192, t = idx % 8192;
        int v = t / 64, r = t % 64;
        val = (r < RS) ? sigma[(a * RS + r) * NV + v] : 0.f;
    } else if (idx < BF_E) {                    // featT
        int j = idx - FEAT_E;
        int a = j / 20480, t = j % 20480;
        int v = t / 160, r = t % 160;
        val = (r < RC) ? feature[(a * RC + r) * NV + v] : 0.f;
    } else if (idx < W1_E) {                    // B frags
        int j = idx - BF_E;
        int frag = j >> 9, li = (j >> 3) & 63, e = j & 7;
        int kt = frag >> 1, nt = frag & 1;
        int k = kt * 32 + (li >> 4) * 8 + e;
        int n = nt * 16 + (li & 15);
        val = (k < RC && n < PP) ? Bm[k * PP + n] : 0.f;
    } else if (idx < W2_E) {                    // W1 frags, permuted rows
        int j = idx - W1_E;
        int frag = j >> 9, li = (j >> 3) & 63, e = j & 7;
        int kt = frag >> 3, nt = frag & 7;
        int kn = kt * 32 + (li >> 4) * 8 + e;   // k in interleaved order
        int n = nt * 16 + (li & 15);
        if (kn < 120) {
            int ko;
            if (kn < 108) { ko = (kn & 3) * PP + (kn >> 2); }            // feats: e*27 + c
            else { int t2 = kn - 108; ko = 108 + (t2 & 3) * 3 + (t2 >> 2); } // dirs: 108 + e*3 + dc
            val = W1[ko * CHN + n];
        }
    } else if (idx < W3_E) {                    // W2 frags
        int j = idx - W2_E;
        int frag = j >> 9, li = (j >> 3) & 63, e = j & 7;
        int kt = frag >> 3, nt = frag & 7;
        int k = kt * 32 + (li >> 4) * 8 + e;
        int n = nt * 16 + (li & 15);
        val = W2[k * CHN + n];
    } else {                                    // W3 frags
        int j = idx - W3_E;
        int frag = j >> 9, li = (j >> 3) & 63, e = j & 7;
        int kt = frag;
        int k = kt * 32 + (li >> 4) * 8 + e;
        int n = li & 15;
        val = (n < 3) ? W3[k * 3 + n] : 0.f;
    }
    ws[idx] = f2bf(val);
}

// ---------------- main fused kernel: 1 wave / 64 points per block ----------------
__global__ __launch_bounds__(64, 2)
void tensorf_main(const float* __restrict__ xyz, const float* __restrict__ dird,
                  const float* __restrict__ voxel,
                  const float* __restrict__ b1, const float* __restrict__ b2,
                  const float* __restrict__ b3,
                  const short* __restrict__ ws, float* __restrict__ out, int Np) {
    __shared__ float voxs[3 * NV];
    __shared__ char  X[64 * 256];   // 64 pts x 128 bf16, XOR-swizzled (chunk ^= row&7)

    const int tid = threadIdx.x;
    const int quad = tid >> 4, lane16 = tid & 15;
    const int blockbase = blockIdx.x * 64;

    for (int i = tid; i < 3 * NV; i += 64) voxs[i] = voxel[i];
    __syncthreads();

    const short* SIGT  = ws + SIG_E;
    const short* FEATT = ws + FEAT_E;
    const short* BFr   = ws + BF_E;

    // hoist B fragments (5 kt x 2 nt)
    short8 bfr[5][2];
#pragma unroll
    for (int kt = 0; kt < 5; ++kt)
#pragma unroll
        for (int nt = 0; nt < 2; ++nt)
            bfr[kt][nt] = *(const short8*)(BFr + ((kt * 2 + nt) * 64 + tid) * 8);

    // ---------------- phase A: 4 passes x 16 points ----------------
#pragma unroll 1
    for (int q = 0; q < 4; ++q) {
        const int rowbase = q * 16;
        const int p = blockbase + rowbase + lane16;

        int ipb[3]; float we[3];
#pragma unroll
        for (int a = 0; a < 3; ++a) {
            float x = xyz[p * 3 + a];
            int ind = (int)ceilf(x * 127.f);
            ind = min(max(ind, 0), 128);
            while (ind > 0 && voxs[a * NV + ind - 1] >= x) --ind;   // searchsorted-left fixup
            while (ind < 128 && voxs[a * NV + ind] < x) ++ind;
            int il = min(max(ind - 1, 0), 127);
            int ir = min(ind, 127);
            float vl = voxs[a * NV + il], vr = voxs[a * NV + ir];
            float w = (x - vl) / (vr - vl + 1e-6f);
            we[a] = (il == 127) ? 1.f : w;      // il==ir==127 edge: pick right neighbor
            ipb[a] = min(il, 126);
        }

        // ---- sigma: lane covers ranks quad*8+j (+32*kt) of its point ----
        float sig = 0.f;
#pragma unroll
        for (int kt = 0; kt < 2; ++kt) {
            float pr[8];
#pragma unroll
            for (int a = 0; a < 3; ++a) {
                const short* rl = SIGT + (a * NV + ipb[a]) * 64 + kt * 32 + quad * 8;
                short8 lo = *(const short8*)rl;
                short8 hi = *(const short8*)(rl + 64);
#pragma unroll
                for (int j = 0; j < 8; ++j) {
                    float fl = bf2f(lo[j]);
                    float s = fmaf(bf2f(hi[j]) - fl, we[a], fl);
                    pr[j] = (a == 0) ? s : pr[j] * s;
                }
            }
#pragma unroll
            for (int j = 0; j < 8; ++j) sig += pr[j];
        }
        sig += __shfl_xor(sig, 16);
        sig += __shfl_xor(sig, 32);
        if (tid < 16) out[p] = log1pf(expf(sig - 5.f));   // softplus(sig + bias)

        // ---- feats = fprod @ B via MFMA (A-frag computed in-place) ----
        f32x4 acc0 = {0.f, 0.f, 0.f, 0.f}, acc1 = {0.f, 0.f, 0.f, 0.f};
#pragma unroll
        for (int kt = 0; kt < 5; ++kt) {
            float pr[8];
#pragma unroll
            for (int a = 0; a < 3; ++a) {
                const short* rl = FEATT + (a * NV + ipb[a]) * 160 + kt * 32 + quad * 8;
                short8 lo = *(const short8*)rl;
                short8 hi = *(const short8*)(rl + 160);
#pragma unroll
                for (int j = 0; j < 8; ++j) {
                    float fl = bf2f(lo[j]);
                    float s = fmaf(bf2f(hi[j]) - fl, we[a], fl);
                    pr[j] = (a == 0) ? s : pr[j] * s;
                }
            }
            short8 af;
#pragma unroll
            for (int j = 0; j < 8; ++j) af[j] = f2bf(pr[j]);
            acc0 = __builtin_amdgcn_mfma_f32_16x16x32_bf16(af, bfr[kt][0], acc0, 0, 0, 0);
            acc1 = __builtin_amdgcn_mfma_f32_16x16x32_bf16(af, bfr[kt][1], acc1, 0, 0, 0);
        }

        // ---- encode feats -> X (interleaved [sin f, cos f, sin 2f, cos 2f] per c) ----
#pragma unroll
        for (int nt = 0; nt < 2; ++nt) {
            int c = nt * 16 + lane16;
            f32x4 A = nt ? acc1 : acc0;
            if (c < PP) {
#pragma unroll
                for (int j = 0; j < 4; ++j) {
                    int row = rowbase + quad * 4 + j;    // D-frag row
                    float f = A[j];
                    float s1 = __sinf(f), c1 = __cosf(f);
                    float s2 = __sinf(2.f * f), c2 = __cosf(2.f * f);
                    unsigned int w0 = (unsigned int)(unsigned short)f2bf(s1) |
                                      ((unsigned int)(unsigned short)f2bf(c1) << 16);
                    unsigned int w1 = (unsigned int)(unsigned short)f2bf(s2) |
                                      ((unsigned int)(unsigned short)f2bf(c2) << 16);
                    int byte = c * 8;
                    int chunk = byte >> 4, off = byte & 15;
                    *(u32x2*)(X + row * 256 + ((chunk ^ (row & 7)) << 4) + off) = u32x2{w0, w1};
                }
            }
        }
        // ---- dirs encode (quads 0..2) + zero-pad cols 120..127 (quad 3) ----
        {
            int row = rowbase + lane16;
            if (quad < 3) {
                float d = dird[p * 3 + quad];
                float s1 = __sinf(d), c1 = __cosf(d);
                float s2 = __sinf(2.f * d), c2 = __cosf(2.f * d);
                unsigned int w0 = (unsigned int)(unsigned short)f2bf(s1) |
                                  ((unsigned int)(unsigned short)f2bf(c1) << 16);
                unsigned int w1 = (unsigned int)(unsigned short)f2bf(s2) |
                                  ((unsigned int)(unsigned short)f2bf(c2) << 16);
                int byte = 216 + 8 * quad;
                int chunk = byte >> 4, off = byte & 15;
                *(u32x2*)(X + row * 256 + ((chunk ^ (row & 7)) << 4) + off) = u32x2{w0, w1};
            } else {
                int addr = row * 256 + ((15 ^ (row & 7)) << 4);
                *(u32x4*)(X + addr) = u32x4{0u, 0u, 0u, 0u};
            }
        }
    }
    __syncthreads();

    // ---------------- phase B: MLP via MFMA, M=64 (4 tiles), per-wave local ----------------
    const short* W1F = ws + W1_E;
    const short* W2F = ws + W2_E;
    const short* W3F = ws + W3_E;

#pragma unroll 1
    for (int layer = 0; layer < 2; ++layer) {
        const short* WF = layer ? W2F : W1F;
        const float* bb = layer ? b2 : b1;

        short8 af[4][4];
#pragma unroll
        for (int m = 0; m < 4; ++m)
#pragma unroll
            for (int kt = 0; kt < 4; ++kt) {
                int row = m * 16 + lane16;
                int chunk = kt * 4 + quad;
                af[m][kt] = *(const short8*)(X + row * 256 + ((chunk ^ (row & 7)) << 4));
            }

        f32x4 acc[4][8];
#pragma unroll
        for (int m = 0; m < 4; ++m)
#pragma unroll
            for (int nt = 0; nt < 8; ++nt) acc[m][nt] = {0.f, 0.f, 0.f, 0.f};

#pragma unroll
        for (int nt = 0; nt < 8; ++nt) {
            short8 wf[4];
#pragma unroll
            for (int kt = 0; kt < 4; ++kt)
                wf[kt] = *(const short8*)(WF + ((kt * 8 + nt) * 64 + tid) * 8);
#pragma unroll
            for (int m = 0; m < 4; ++m)
#pragma unroll
                for (int kt = 0; kt < 4; ++kt)
                    acc[m][nt] = __builtin_amdgcn_mfma_f32_16x16x32_bf16(af[m][kt], wf[kt], acc[m][nt], 0, 0, 0);
        }
        __syncthreads();

        // epilogue: +bias, leaky relu, bf16, back into X
#pragma unroll
        for (int nt = 0; nt < 8; ++nt) {
            float bvv = bb[nt * 16 + lane16];
#pragma unroll
            for (int m = 0; m < 4; ++m) {
#pragma unroll
                for (int j = 0; j < 4; ++j) {
                    float v = acc[m][nt][j] + bvv;
                    v = fmaxf(v, 0.01f * v);            // leaky relu
                    int row = m * 16 + quad * 4 + j;
                    int byte = (nt * 16 + lane16) * 2;
                    int chunk = byte >> 4, off = byte & 15;
                    *(short*)(X + row * 256 + ((chunk ^ (row & 7)) << 4) + off) = f2bf(v);
                }
            }
        }
        __syncthreads();
    }

    // ---- layer 3: 128 -> 3 (+sigmoid) ----
    {
        short8 af[4][4];
#pragma unroll
        for (int m = 0; m < 4; ++m)
#pragma unroll
            for (int kt = 0; kt < 4; ++kt) {
                int row = m * 16 + lane16;
                int chunk = kt * 4 + quad;
                af[m][kt] = *(const short8*)(X + row * 256 + ((chunk ^ (row & 7)) << 4));
            }
        short8 wf3[4];
#pragma unroll
        for (int kt = 0; kt < 4; ++kt)
            wf3[kt] = *(const short8*)(W3F + (kt * 64 + tid) * 8);

        f32x4 acc3[4];
#pragma unroll
        for (int m = 0; m < 4; ++m) acc3[m] = {0.f, 0.f, 0.f, 0.f};
#pragma unroll
        for (int m = 0; m < 4; ++m)
#pragma unroll
            for (int kt = 0; kt < 4; ++kt)
                acc3[m] = __builtin_amdgcn_mfma_f32_16x16x32_bf16(af[m][kt], wf3[kt], acc3[m], 0, 0, 0);

        if (lane16 < 3) {
            float bvv = b3[lane16];
#pragma unroll
            for (int m = 0; m < 4; ++m) {
#pragma unroll
                for (int j = 0; j < 4; ++j) {
                    float v = acc3[m][j] + bvv;
                    float r = 1.f / (1.f + expf(-v));   // sigmoid
                    int row = m * 16 + quad * 4 + j;
                    out[Np + (blockbase + row) * 3 + lane16] = r;
                }
            }
        }
    }
}

// ---------------- launch ----------------
extern "C" void kernel_launch(void* const* d_in, const int* in_sizes, int n_in,
                              void* d_out, int out_size, void* d_ws, size_t ws_size,
                              hipStream_t stream) {
    (void)n_in; (void)out_size; (void)ws_size;
    const float* xyz      = (const float*)d_in[0];
    const float* dird     = (const float*)d_in[1];
    const float* voxel    = (const float*)d_in[2];
    const float* sigma    = (const float*)d_in[3];
    const float* feature  = (const float*)d_in[4];
    const float* Bm       = (const float*)d_in[5];
    const float* W1       = (const float*)d_in[6];
    const float* b1       = (const float*)d_in[7];
    const float* W2       = (const float*)d_in[8];
    const float* b2       = (const float*)d_in[9];
    const float* W3       = (const float*)d_in[10];
    const float* b3       = (const float*)d_in[11];
    float* out = (float*)d_out;
    short* ws  = (short*)d_ws;

    const int Np = in_sizes[0] / 3;   // 524288

    prep_kernel<<<(TOT_E + 255) / 256, 256, 0, stream>>>(sigma, feature, Bm, W1, W2, W3, ws);
    tensorf_main<<<Np / 64, 64, 0, stream>>>(xyz, dird, voxel, b1, b2, b3, ws, out, Np);
}

// Round 2
// 185.672 us; speedup vs baseline: 2.1857x; 2.1857x over previous
//
#include <hip/hip_runtime.h>
#include <cstdint>

// ---------------- problem constants ----------------
constexpr int RS  = 48;    // sigma ranks
constexpr int RC  = 144;   // feature ranks
constexpr int PP  = 27;    // feats dim
constexpr int NV  = 128;   // voxels per axis
constexpr int CHN = 128;   // MLP hidden

// ---------------- ws layout (bf16 element offsets) ----------------
constexpr int SIG_E  = 0;                      // sigmaT [3][128][64]   = 24576
constexpr int FEAT_E = 24576;                  // featT  [3][128][160]  = 61440
constexpr int BF_E   = 86016;                  // B frags [5][2][64][8] = 5120
constexpr int W1_E   = 91136;                  // W1 frags [4][8][64][8]= 16384
constexpr int W2_E   = 107520;                 // W2 frags              = 16384
constexpr int W3_E   = 123904;                 // W3 frags [4][64][8]   = 2048
constexpr int TOT_E  = 125952;

typedef __attribute__((ext_vector_type(8))) short short8;
typedef __attribute__((ext_vector_type(4))) float f32x4;
typedef __attribute__((ext_vector_type(2))) unsigned int u32x2;
typedef __attribute__((ext_vector_type(4))) unsigned int u32x4;

__device__ __forceinline__ short f2bf(float f) {
    unsigned int u = __builtin_bit_cast(unsigned int, f);
    u += 0x7fffu + ((u >> 16) & 1u);           // RNE
    return (short)(u >> 16);
}
__device__ __forceinline__ float bf2f(short s) {
    unsigned int u = ((unsigned int)(unsigned short)s) << 16;
    return __builtin_bit_cast(float, u);
}

// ---------------- prep: build bf16 tables + fragment-layout weights ----------------
__global__ void prep_kernel(const float* __restrict__ sigma, const float* __restrict__ feature,
                            const float* __restrict__ Bm, const float* __restrict__ W1,
                            const float* __restrict__ W2, const float* __restrict__ W3,
                            short* __restrict__ ws) {
    int idx = blockIdx.x * 256 + threadIdx.x;
    if (idx >= TOT_E) return;
    float val = 0.f;
    if (idx < FEAT_E) {                         // sigmaT
        int a = idx / 8192, t = idx % 8192;
        int v = t / 64, r = t % 64;
        val = (r < RS) ? sigma[(a * RS + r) * NV + v] : 0.f;
    } else if (idx < BF_E) {                    // featT
        int j = idx - FEAT_E;
        int a = j / 20480, t = j % 20480;
        int v = t / 160, r = t % 160;
        val = (r < RC) ? feature[(a * RC + r) * NV + v] : 0.f;
    } else if (idx < W1_E) {                    // B frags
        int j = idx - BF_E;
        int frag = j >> 9, li = (j >> 3) & 63, e = j & 7;
        int kt = frag >> 1, nt = frag & 1;
        int k = kt * 32 + (li >> 4) * 8 + e;
        int n = nt * 16 + (li & 15);
        val = (k < RC && n < PP) ? Bm[k * PP + n] : 0.f;
    } else if (idx < W2_E) {                    // W1 frags, permuted rows
        int j = idx - W1_E;
        int frag = j >> 9, li = (j >> 3) & 63, e = j & 7;
        int kt = frag >> 3, nt = frag & 7;
        int kn = kt * 32 + (li >> 4) * 8 + e;   // k in interleaved order
        int n = nt * 16 + (li & 15);
        if (kn < 120) {
            int ko;
            if (kn < 108) { ko = (kn & 3) * PP + (kn >> 2); }            // feats: e*27 + c
            else { int t2 = kn - 108; ko = 108 + (t2 & 3) * 3 + (t2 >> 2); } // dirs
            val = W1[ko * CHN + n];
        }
    } else if (idx < W3_E) {                    // W2 frags
        int j = idx - W2_E;
        int frag = j >> 9, li = (j >> 3) & 63, e = j & 7;
        int kt = frag >> 3, nt = frag & 7;
        int k = kt * 32 + (li >> 4) * 8 + e;
        int n = nt * 16 + (li & 15);
        val = W2[k * CHN + n];
    } else {                                    // W3 frags
        int j = idx - W3_E;
        int frag = j >> 9, li = (j >> 3) & 63, e = j & 7;
        int kt = frag;
        int k = kt * 32 + (li >> 4) * 8 + e;
        int n = li & 15;
        val = (n < 3) ? W3[k * 3 + n] : 0.f;
    }
    ws[idx] = f2bf(val);
}

// ---------------- main fused kernel: 2 waves/block, 32 points per wave ----------------
// LDS per block: 2 x 8KB X-tiles + 1.5KB voxel grid = 17.9KB -> 9 blocks/CU = 18 waves
// (vs round-1's 1-wave/17.9KB = 8 waves/CU). VGPR capped at 128 (16 waves/CU).
__global__ __launch_bounds__(128, 4)
void tensorf_main(const float* __restrict__ xyz, const float* __restrict__ dird,
                  const float* __restrict__ voxel,
                  const float* __restrict__ b1, const float* __restrict__ b2,
                  const float* __restrict__ b3,
                  const short* __restrict__ ws, float* __restrict__ out, int Np) {
    __shared__ float voxs[3 * NV];
    __shared__ char  X[2 * 32 * 256];  // per-wave 32 pts x 128 bf16, XOR-swizzled

    const int tid = threadIdx.x;
    const int wid = tid >> 6;
    const int lane = tid & 63;
    const int quad = lane >> 4, lane16 = lane & 15;
    const int wavebase = blockIdx.x * 64 + wid * 32;
    char* Xw = X + wid * 32 * 256;

    for (int i = tid; i < 3 * NV; i += 128) voxs[i] = voxel[i];
    __syncthreads();

    const short* SIGT  = ws + SIG_E;
    const short* FEATT = ws + FEAT_E;
    const short* BFr   = ws + BF_E;

    // ---------------- phase A: 2 passes x 16 points ----------------
#pragma unroll 1
    for (int q = 0; q < 2; ++q) {
        const int rowbase = q * 16;
        const int p = wavebase + rowbase + lane16;

        int ipb[3]; float we[3];
#pragma unroll
        for (int a = 0; a < 3; ++a) {
            float x = xyz[p * 3 + a];
            int ind = (int)ceilf(x * 127.f);
            ind = min(max(ind, 0), 128);
            while (ind > 0 && voxs[a * NV + ind - 1] >= x) --ind;   // searchsorted-left fixup
            while (ind < 128 && voxs[a * NV + ind] < x) ++ind;
            int il = min(max(ind - 1, 0), 127);
            int ir = min(ind, 127);
            float vl = voxs[a * NV + il], vr = voxs[a * NV + ir];
            float w = (x - vl) / (vr - vl + 1e-6f);
            we[a] = (il == 127) ? 1.f : w;      // il==ir==127 edge
            ipb[a] = min(il, 126);
        }

        // ---- sigma ----
        float sig = 0.f;
#pragma unroll
        for (int kt = 0; kt < 2; ++kt) {
            float pr[8];
#pragma unroll
            for (int a = 0; a < 3; ++a) {
                const short* rl = SIGT + (a * NV + ipb[a]) * 64 + kt * 32 + quad * 8;
                short8 lo = *(const short8*)rl;
                short8 hi = *(const short8*)(rl + 64);
#pragma unroll
                for (int j = 0; j < 8; ++j) {
                    float fl = bf2f(lo[j]);
                    float s = fmaf(bf2f(hi[j]) - fl, we[a], fl);
                    pr[j] = (a == 0) ? s : pr[j] * s;
                }
            }
#pragma unroll
            for (int j = 0; j < 8; ++j) sig += pr[j];
        }
        sig += __shfl_xor(sig, 16);
        sig += __shfl_xor(sig, 32);
        if (lane < 16) out[p] = log1pf(expf(sig - 5.f));   // softplus(sig + bias)

        // ---- feats = fprod @ B via MFMA ----
        f32x4 acc0 = {0.f, 0.f, 0.f, 0.f}, acc1 = {0.f, 0.f, 0.f, 0.f};
#pragma unroll
        for (int kt = 0; kt < 5; ++kt) {
            float pr[8];
#pragma unroll
            for (int a = 0; a < 3; ++a) {
                const short* rl = FEATT + (a * NV + ipb[a]) * 160 + kt * 32 + quad * 8;
                short8 lo = *(const short8*)rl;
                short8 hi = *(const short8*)(rl + 160);
#pragma unroll
                for (int j = 0; j < 8; ++j) {
                    float fl = bf2f(lo[j]);
                    float s = fmaf(bf2f(hi[j]) - fl, we[a], fl);
                    pr[j] = (a == 0) ? s : pr[j] * s;
                }
            }
            short8 af;
#pragma unroll
            for (int j = 0; j < 8; ++j) af[j] = f2bf(pr[j]);
            short8 b0 = *(const short8*)(BFr + ((kt * 2 + 0) * 64 + lane) * 8);
            short8 b1f = *(const short8*)(BFr + ((kt * 2 + 1) * 64 + lane) * 8);
            acc0 = __builtin_amdgcn_mfma_f32_16x16x32_bf16(af, b0, acc0, 0, 0, 0);
            acc1 = __builtin_amdgcn_mfma_f32_16x16x32_bf16(af, b1f, acc1, 0, 0, 0);
        }

        // ---- encode feats -> X ----
#pragma unroll
        for (int nt = 0; nt < 2; ++nt) {
            int c = nt * 16 + lane16;
            f32x4 A = nt ? acc1 : acc0;
            if (c < PP) {
#pragma unroll
                for (int j = 0; j < 4; ++j) {
                    int row = rowbase + quad * 4 + j;    // D-frag row
                    float f = A[j];
                    float s1 = __sinf(f), c1 = __cosf(f);
                    float s2 = __sinf(2.f * f), c2 = __cosf(2.f * f);
                    unsigned int w0 = (unsigned int)(unsigned short)f2bf(s1) |
                                      ((unsigned int)(unsigned short)f2bf(c1) << 16);
                    unsigned int w1 = (unsigned int)(unsigned short)f2bf(s2) |
                                      ((unsigned int)(unsigned short)f2bf(c2) << 16);
                    int byte = c * 8;
                    int chunk = byte >> 4, off = byte & 15;
                    *(u32x2*)(Xw + row * 256 + ((chunk ^ (row & 7)) << 4) + off) = u32x2{w0, w1};
                }
            }
        }
        // ---- dirs encode + zero-pad cols 120..127 ----
        {
            int row = rowbase + lane16;
            if (quad < 3) {
                float d = dird[p * 3 + quad];
                float s1 = __sinf(d), c1 = __cosf(d);
                float s2 = __sinf(2.f * d), c2 = __cosf(2.f * d);
                unsigned int w0 = (unsigned int)(unsigned short)f2bf(s1) |
                                  ((unsigned int)(unsigned short)f2bf(c1) << 16);
                unsigned int w1 = (unsigned int)(unsigned short)f2bf(s2) |
                                  ((unsigned int)(unsigned short)f2bf(c2) << 16);
                int byte = 216 + 8 * quad;
                int chunk = byte >> 4, off = byte & 15;
                *(u32x2*)(Xw + row * 256 + ((chunk ^ (row & 7)) << 4) + off) = u32x2{w0, w1};
            } else {
                int addr = row * 256 + ((15 ^ (row & 7)) << 4);
                *(u32x4*)(Xw + addr) = u32x4{0u, 0u, 0u, 0u};
            }
        }
    }
    __syncthreads();

    // ---------------- phase B: per-wave MLP, M=32 (2 tiles) ----------------
    const short* W1F = ws + W1_E;
    const short* W2F = ws + W2_E;
    const short* W3F = ws + W3_E;

#pragma unroll 1
    for (int layer = 0; layer < 2; ++layer) {
        const short* WF = layer ? W2F : W1F;
        const float* bb = layer ? b2 : b1;

        short8 af[2][4];
#pragma unroll
        for (int m = 0; m < 2; ++m)
#pragma unroll
            for (int kt = 0; kt < 4; ++kt) {
                int row = m * 16 + lane16;
                int chunk = kt * 4 + quad;
                af[m][kt] = *(const short8*)(Xw + row * 256 + ((chunk ^ (row & 7)) << 4));
            }

        // per-nt epilogue keeps accumulators at 2 x f32x4
#pragma unroll 1
        for (int nt = 0; nt < 8; ++nt) {
            short8 wf[4];
#pragma unroll
            for (int kt = 0; kt < 4; ++kt)
                wf[kt] = *(const short8*)(WF + ((kt * 8 + nt) * 64 + lane) * 8);
            f32x4 acc[2];
#pragma unroll
            for (int m = 0; m < 2; ++m) acc[m] = {0.f, 0.f, 0.f, 0.f};
#pragma unroll
            for (int m = 0; m < 2; ++m)
#pragma unroll
                for (int kt = 0; kt < 4; ++kt)
                    acc[m] = __builtin_amdgcn_mfma_f32_16x16x32_bf16(af[m][kt], wf[kt], acc[m], 0, 0, 0);

            float bvv = bb[nt * 16 + lane16];
#pragma unroll
            for (int m = 0; m < 2; ++m) {
#pragma unroll
                for (int j = 0; j < 4; ++j) {
                    float v = acc[m][j] + bvv;
                    v = fmaxf(v, 0.01f * v);            // leaky relu
                    int row = m * 16 + quad * 4 + j;
                    int byte = (nt * 16 + lane16) * 2;
                    int chunk = byte >> 4, off = byte & 15;
                    *(short*)(Xw + row * 256 + ((chunk ^ (row & 7)) << 4) + off) = f2bf(v);
                }
            }
        }
        __syncthreads();
    }

    // ---- layer 3: 128 -> 3 (+sigmoid) ----
    {
        short8 af[2][4];
#pragma unroll
        for (int m = 0; m < 2; ++m)
#pragma unroll
            for (int kt = 0; kt < 4; ++kt) {
                int row = m * 16 + lane16;
                int chunk = kt * 4 + quad;
                af[m][kt] = *(const short8*)(Xw + row * 256 + ((chunk ^ (row & 7)) << 4));
            }
        short8 wf3[4];
#pragma unroll
        for (int kt = 0; kt < 4; ++kt)
            wf3[kt] = *(const short8*)(W3F + (kt * 64 + lane) * 8);

        f32x4 acc3[2];
#pragma unroll
        for (int m = 0; m < 2; ++m) acc3[m] = {0.f, 0.f, 0.f, 0.f};
#pragma unroll
        for (int m = 0; m < 2; ++m)
#pragma unroll
            for (int kt = 0; kt < 4; ++kt)
                acc3[m] = __builtin_amdgcn_mfma_f32_16x16x32_bf16(af[m][kt], wf3[kt], acc3[m], 0, 0, 0);

        if (lane16 < 3) {
            float bvv = b3[lane16];
#pragma unroll
            for (int m = 0; m < 2; ++m) {
#pragma unroll
                for (int j = 0; j < 4; ++j) {
                    float v = acc3[m][j] + bvv;
                    float r = 1.f / (1.f + expf(-v));   // sigmoid
                    int row = m * 16 + quad * 4 + j;
                    out[Np + (wavebase + row) * 3 + lane16] = r;
                }
            }
        }
    }
}

// ---------------- launch ----------------
extern "C" void kernel_launch(void* const* d_in, const int* in_sizes, int n_in,
                              void* d_out, int out_size, void* d_ws, size_t ws_size,
                              hipStream_t stream) {
    (void)n_in; (void)out_size; (void)ws_size;
    const float* xyz      = (const float*)d_in[0];
    const float* dird     = (const float*)d_in[1];
    const float* voxel    = (const float*)d_in[2];
    const float* sigma    = (const float*)d_in[3];
    const float* feature  = (const float*)d_in[4];
    const float* Bm       = (const float*)d_in[5];
    const float* W1       = (const float*)d_in[6];
    const float* b1       = (const float*)d_in[7];
    const float* W2       = (const float*)d_in[8];
    const float* b2       = (const float*)d_in[9];
    const float* W3       = (const float*)d_in[10];
    const float* b3       = (const float*)d_in[11];
    float* out = (float*)d_out;
    short* ws  = (short*)d_ws;

    const int Np = in_sizes[0] / 3;   // 524288

    prep_kernel<<<(TOT_E + 255) / 256, 256, 0, stream>>>(sigma, feature, Bm, W1, W2, W3, ws);
    tensorf_main<<<Np / 64, 128, 0, stream>>>(xyz, dird, voxel, b1, b2, b3, ws, out, Np);
}